// Round 5
// baseline (357.853 us; speedup 1.0000x reference)
//
#include <hip/hip_runtime.h>
#include <math.h>

// PPCALayer fused kernel, MI355X (gfx950) — wave-autonomous (R2 body,
// re-grouped into 1024-thread blocks for DRAM row locality).
// x: [B=64, C=256, HW=3136] fp32, weight: [3136, 15] fp32, out same as x.
//
// Per pixel (b,s): 15 multi-scale channel-group means (scales 1,2,4,8 over
// contiguous channel groups) -> normalize across the 15 features (ddof=0)
// -> dot with weight[s,:] -> sigmoid -> scale x[b,:,s].
//
// Design (R2, measured 91 us kernel @ 4.5 TB/s): each WAVE owns 16 spatials
// x 256 channels. lane = (c0<<2)|s4: c0=lane>>2 owns channels [16c0,16c0+16),
// s4=lane&3 owns 4 spatials as one float4. Tile (16 KB) lives in registers
// (16 x float4, kernel-body array -> SROA; NEVER pass it to helpers — R3's
// function-decay demoted it to scratch, VGPR_Count 48 + 2x FETCH). All
// reductions are __shfl_xor butterflies (distances 4..32 preserve lane&3).
// ZERO LDS, ZERO barriers.
//
// R5 change vs R2 (geometry only, body identical):
//   block = 1024 threads (16 waves), grid = 784. A block's waves jointly
//   issue 1 KB contiguous per channel row (16 x 64 B, same CU, same time)
//   vs 256 B with 256-thread blocks. Theory: reads are DRAM row-activate
//   limited (~256 B/ACT -> ~4.5 TB/s observed; fills at 2 KB/ACT hit 6.5);
//   1 KB per activate should recover most of the gap.
// R4's nontemporal loads/stores REVERTED: they regressed 91 -> 103 us by
// defeating L2/L3 residency (steady-state reads are cache-served here).
//
// Algebra: mean of the 15 features = tot/256 = scale-1 feature exactly, so
// its normalized value is 0 and weight[:,0] is dead. Distributed dot /
// variance with replication corrections (t1 on 2 lanes, t2 on 4, t3 on 8).

constexpr int C_   = 256;
constexpr int HW_  = 3136;   // 56*56
constexpr int B_   = 64;
constexpr int SPW_ = 16;            // spatials per wave
constexpr int TPI_ = HW_ / SPW_;    // 196 tiles per image
constexpr int WPB_ = 16;            // waves per block (block = 1024)

__device__ __forceinline__ float4 shx4(float4 a, int m) {
  float4 r;
  r.x = __shfl_xor(a.x, m);
  r.y = __shfl_xor(a.y, m);
  r.z = __shfl_xor(a.z, m);
  r.w = __shfl_xor(a.w, m);
  return r;
}
__device__ __forceinline__ float4 add4(float4 a, float4 b) {
  float4 r; r.x = a.x + b.x; r.y = a.y + b.y; r.z = a.z + b.z; r.w = a.w + b.w;
  return r;
}

__global__ __launch_bounds__(1024, 4) void ppca_fused(
    const float* __restrict__ x, const float* __restrict__ wgt,
    float* __restrict__ out)
{
  const int lane = threadIdx.x & 63;
  const int wav  = threadIdx.x >> 6;
  const unsigned W   = blockIdx.x * WPB_ + wav;   // 0..12543
  const unsigned b   = W / TPI_;                  // magic-mul div
  const unsigned til = W - b * TPI_;
  const int sp0 = til * SPW_;

  const int s4 = lane & 3;    // float4 column (4 spatials)
  const int c0 = lane >> 2;   // 16-channel group, 0..15

  const size_t off = (size_t)b * C_ * HW_ + (size_t)c0 * 16 * HW_
                   + (size_t)sp0 + (size_t)(s4 << 2);
  const float* xb = x + off;
  float* ob = out + off;

  // ---- Load the wave's tile: 16 float4 per lane, registers only.
  // Per instruction: 16 channel rows x 64 B (4 lanes x 16 B), line-aligned;
  // the block's 16 waves together cover 1 KB contiguous per channel row.
  float4 v[16];
  #pragma unroll
  for (int i = 0; i < 16; ++i)
    v[i] = *(const float4*)(xb + (size_t)i * HW_);

  // ---- Per-lane partial: sum of its 16 channels, per spatial component.
  float4 ps = v[0];
  #pragma unroll
  for (int i = 1; i < 16; ++i) ps = add4(ps, v[i]);

  // ---- Butterfly up the group-sum hierarchy (per spatial component):
  // t1 = 32-group sum, t2 = 64-group, t3 = 128-group, t4 = total(256).
  const float4 t1 = add4(ps, shx4(ps, 4));
  const float4 t2 = add4(t1, shx4(t1, 8));
  const float4 t3 = add4(t2, shx4(t2, 16));
  const float4 t4 = add4(t3, shx4(t3, 32));

  // ---- Centered features (m uniform within the s4 class).
  float4 m4;
  m4.x = t4.x * (1.f / 256.f); m4.y = t4.y * (1.f / 256.f);
  m4.z = t4.z * (1.f / 256.f); m4.w = t4.w * (1.f / 256.f);

  // Feature order in weight row: [0:tot(dead), 1-2:128s, 3-6:64s, 7-14:32s].
  const float* wr = wgt + (size_t)sp0 * 15;
  const int i128 = 1 + (c0 >> 3);
  const int i64  = 3 + (c0 >> 2);
  const int i32  = 7 + (c0 >> 1);

  float4 zn, sq;
#define DO_SPATIAL(J, T1c, T2c, T3c, Mc, ZNc, SQc)                           \
  {                                                                          \
    const float* wp = wr + ((s4 << 2) + J) * 15;                             \
    const float w128 = wp[i128];                                             \
    const float w64  = wp[i64];                                              \
    const float w32  = wp[i32];                                              \
    const float u1 = T1c * (1.f / 32.f)  - Mc;                               \
    const float u2 = T2c * (1.f / 64.f)  - Mc;                               \
    const float u3 = T3c * (1.f / 128.f) - Mc;                               \
    ZNc = u1 * w32 * 0.5f + u2 * w64 * 0.25f + u3 * w128 * 0.125f;           \
    SQc = u1 * u1 * 0.5f + u2 * u2 * 0.25f + u3 * u3 * 0.125f;               \
  }
  DO_SPATIAL(0, t1.x, t2.x, t3.x, m4.x, zn.x, sq.x)
  DO_SPATIAL(1, t1.y, t2.y, t3.y, m4.y, zn.y, sq.y)
  DO_SPATIAL(2, t1.z, t2.z, t3.z, m4.z, zn.z, sq.z)
  DO_SPATIAL(3, t1.w, t2.w, t3.w, m4.w, zn.w, sq.w)
#undef DO_SPATIAL

  // ---- Butterfly-sum the accumulators across the 16 lanes sharing s4.
  #pragma unroll
  for (int d = 4; d <= 32; d <<= 1) {
    zn = add4(zn, shx4(zn, d));
    sq = add4(sq, shx4(sq, d));
  }

  // ---- Gate per spatial: var = sq/15; z = zn/std; gate = sigmoid(z).
  float4 g;
#define GATE(ZNc, SQc, Gc)                                                   \
  {                                                                          \
    const float inv = 1.f / sqrtf(SQc * (1.f / 15.f));                       \
    Gc = 1.f / (1.f + __expf(-(ZNc * inv)));                                 \
  }
  GATE(zn.x, sq.x, g.x)
  GATE(zn.y, sq.y, g.y)
  GATE(zn.z, sq.z, g.z)
  GATE(zn.w, sq.w, g.w)
#undef GATE

  // ---- Multiply registers by gate, store (same coalesced pattern as load).
  #pragma unroll
  for (int i = 0; i < 16; ++i) {
    float4 vv = v[i];
    vv.x *= g.x; vv.y *= g.y; vv.z *= g.z; vv.w *= g.w;
    *(float4*)(ob + (size_t)i * HW_) = vv;
  }
}

extern "C" void kernel_launch(void* const* d_in, const int* in_sizes, int n_in,
                              void* d_out, int out_size, void* d_ws, size_t ws_size,
                              hipStream_t stream) {
  const float* x = (const float*)d_in[0];      // [64,256,3136] fp32
  const float* w = (const float*)d_in[1];      // [3136,15] fp32
  float* out = (float*)d_out;                  // [64,256,3136] fp32
  (void)in_sizes; (void)n_in; (void)out_size; (void)d_ws; (void)ws_size;

  dim3 grid(B_ * TPI_ / WPB_);   // 12544 waves / 16 = 784 blocks
  dim3 block(1024);
  ppca_fused<<<grid, block, 0, stream>>>(x, w, out);
}

// Round 6
// 340.786 us; speedup vs baseline: 1.0501x; 1.0501x over previous
//
#include <hip/hip_runtime.h>
#include <math.h>

// PPCALayer fused kernel, MI355X (gfx950) — R6: full-cache-line access.
// x: [B=64, C=256, HW=3136] fp32, weight: [3136, 15] fp32, out same as x.
//
// Per pixel (b,s): 15 multi-scale channel-group means (scales 1,2,4,8 over
// contiguous channel groups) -> normalize across the 15 features (ddof=0)
// -> dot with weight[s,:] -> sigmoid -> scale x[b,:,s].
//
// Kernel-time ladder (total - 252us of harness fills): R2 91us (4.5 TB/s),
// R4 nt 103us (REVERTED: defeats cache), R5 1024-thr blocks 106us
// (REVERTED: 1 block/CU -> coarse whole-CU rounds). Roofline 412MB@6.3 = 65us.
//
// R6 theory: R2's loads were 64 B per channel row per instruction = HALF a
// 128 B line, completed by sibling waves at loosely-coupled times. Remap so
// each instruction covers 256 B contiguous (2 full lines) per row:
//   block = 256 thr = 4 waves, tile = 64 spatials x 256 channels.
//   wave w owns channels [64w, 64w+64); lane = (c0<<4)|s4:
//     c0 = lane>>4 in [0,4): 16-channel sub-block [64w+16c0, +16)
//     s4 = lane&15: spatial float4 [sp0+4*s4, +4)
//   One load instr: 4 channel rows x 256 B contiguous each. Stores likewise.
// The 256-channel reduction crosses waves -> single 2 KB LDS exchange of the
// eight 32-chan sums + ONE __syncthreads (all x-loads already consumed there,
// so the barrier's vmcnt-drain costs nothing). Tile stays in registers
// (16 x float4 in kernel body; NEVER pass to helpers - R3 scratch lesson).
//
// Feature algebra (computed ONCE per c0 class, no replication corrections):
//   g0..g7 = 32-chan block sums (from LDS). T = sum(g), H = g0+g1+g2+g3.
//   mean m = T/256 (= scale-1 feature exactly -> its normalized value is 0,
//   weight[:,0] dead). Lane class c0 contributes features:
//     f[7+2c0] = gA/32, f[8+2c0] = gB/32   (gA=g[2c0], gB=g[2c0+1])
//     f[3+c0]  = (gA+gB)/64
//     c0==1: f[1] = H/128 ; c0==3: f[2] = (T-H)/128
//   zn = sum (f-m)*w, sq = sum (f-m)^2 -> butterfly xor16+xor32 over the
//   4 c0 classes -> var = sq/15, z = zn/sqrt(var), gate = sigmoid(z).

constexpr int C_   = 256;
constexpr int HW_  = 3136;   // 56*56
constexpr int B_   = 64;
constexpr int SPB_ = 64;            // spatials per block
constexpr int TPI_ = HW_ / SPB_;    // 49 tiles per image

__device__ __forceinline__ float4 shx4(float4 a, int m) {
  float4 r;
  r.x = __shfl_xor(a.x, m);
  r.y = __shfl_xor(a.y, m);
  r.z = __shfl_xor(a.z, m);
  r.w = __shfl_xor(a.w, m);
  return r;
}
__device__ __forceinline__ float4 add4(float4 a, float4 b) {
  float4 r; r.x = a.x + b.x; r.y = a.y + b.y; r.z = a.z + b.z; r.w = a.w + b.w;
  return r;
}

__global__ __launch_bounds__(256, 4) void ppca_fused(
    const float* __restrict__ x, const float* __restrict__ wgt,
    float* __restrict__ out)
{
  __shared__ __align__(16) float S[8 * SPB_];   // 2 KB: [g 0..7][spatial 0..63]

  const int lane = threadIdx.x & 63;
  const int wav  = threadIdx.x >> 6;          // 0..3: channels [64w, 64w+64)
  const unsigned blk = blockIdx.x;
  const unsigned b   = blk / TPI_;
  const unsigned til = blk - b * TPI_;
  const int sp0 = til * SPB_;

  const int s4 = lane & 15;   // spatial float4 column (4 spatials)
  const int c0 = lane >> 4;   // 0..3: 16-channel sub-block

  const int chbase = wav * 64 + c0 * 16;
  const size_t base = (size_t)b * C_ * HW_ + (size_t)chbase * HW_
                    + (size_t)sp0 + (size_t)(s4 << 2);
  const float* xb = x + base;
  float* ob = out + base;

  // ---- Load tile: 16 float4/lane, registers only. Per instruction:
  // 4 channel rows x 256 B contiguous (16 lanes x 16 B), line-aligned.
  float4 v[16];
  #pragma unroll
  for (int i = 0; i < 16; ++i)
    v[i] = *(const float4*)(xb + (size_t)i * HW_);

  // ---- Per-lane sum of its 16 channels (per spatial component).
  float4 ps = v[0];
  #pragma unroll
  for (int i = 1; i < 16; ++i) ps = add4(ps, v[i]);

  // ---- xor16 pairs c0 (0,1) and (2,3): 32-channel block sums.
  // c0 in {0,1} -> g(2w) = channels [64w, 64w+32); c0 in {2,3} -> g(2w+1).
  const float4 t32 = add4(ps, shx4(ps, 16));

  // ---- Exchange the eight 32-chan sums through LDS (one writer per g,s4).
  if ((c0 & 1) == 0) {
    const int g = 2 * wav + (c0 >> 1);
    *(float4*)(&S[g * SPB_ + (s4 << 2)]) = t32;
  }
  __syncthreads();   // all x-loads consumed above -> vmcnt drain is free

  // ---- Stream the 8 g's: total T, first-half H; own gA, gB by address.
  float4 T = {0.f, 0.f, 0.f, 0.f};
  float4 H;
  #pragma unroll
  for (int g = 0; g < 8; ++g) {
    const float4 q = *(const float4*)(&S[g * SPB_ + (s4 << 2)]);
    T = add4(T, q);
    if (g == 3) H = T;
  }
  const float4 gA = *(const float4*)(&S[(2 * c0)     * SPB_ + (s4 << 2)]);
  const float4 gB = *(const float4*)(&S[(2 * c0 + 1) * SPB_ + (s4 << 2)]);

  float4 m4;
  m4.x = T.x * (1.f / 256.f); m4.y = T.y * (1.f / 256.f);
  m4.z = T.z * (1.f / 256.f); m4.w = T.w * (1.f / 256.f);

  // ---- Centered features owned by this lane class.
  float4 uA, uB, u64, u128;
#define CF(Fc, Sc, SCALE, Mc) Fc = Sc * (1.f / SCALE) - Mc;
  CF(uA.x, gA.x, 32.f, m4.x) CF(uA.y, gA.y, 32.f, m4.y)
  CF(uA.z, gA.z, 32.f, m4.z) CF(uA.w, gA.w, 32.f, m4.w)
  CF(uB.x, gB.x, 32.f, m4.x) CF(uB.y, gB.y, 32.f, m4.y)
  CF(uB.z, gB.z, 32.f, m4.z) CF(uB.w, gB.w, 32.f, m4.w)
#undef CF
  {
    const float4 g64 = add4(gA, gB);
    u64.x = g64.x * (1.f / 64.f) - m4.x;
    u64.y = g64.y * (1.f / 64.f) - m4.y;
    u64.z = g64.z * (1.f / 64.f) - m4.z;
    u64.w = g64.w * (1.f / 64.f) - m4.w;
  }
  if (c0 == 1) {
    u128.x = H.x * (1.f / 128.f) - m4.x;
    u128.y = H.y * (1.f / 128.f) - m4.y;
    u128.z = H.z * (1.f / 128.f) - m4.z;
    u128.w = H.w * (1.f / 128.f) - m4.w;
  } else if (c0 == 3) {
    u128.x = (T.x - H.x) * (1.f / 128.f) - m4.x;
    u128.y = (T.y - H.y) * (1.f / 128.f) - m4.y;
    u128.z = (T.z - H.z) * (1.f / 128.f) - m4.z;
    u128.w = (T.w - H.w) * (1.f / 128.f) - m4.w;
  } else {
    u128.x = 0.f; u128.y = 0.f; u128.z = 0.f; u128.w = 0.f;
  }

  // ---- sq partial (weight-free), then zn with streamed weight loads.
  float4 sq;
#define SQC(Qc, Ac, Bc, Cc, Dc) Qc = Ac*Ac + Bc*Bc + Cc*Cc + Dc*Dc;
  SQC(sq.x, uA.x, uB.x, u64.x, u128.x)
  SQC(sq.y, uA.y, uB.y, u64.y, u128.y)
  SQC(sq.z, uA.z, uB.z, u64.z, u128.z)
  SQC(sq.w, uA.w, uB.w, u64.w, u128.w)
#undef SQC

  // weight row stride 15; feature indices for this lane class.
  const int iA   = 7 + 2 * c0;
  const int iB   = 8 + 2 * c0;
  const int i64  = 3 + c0;
  const int i128 = 1 + (c0 >> 1);   // only meaningful for odd c0 (u128=0 else)
  const float* wr = wgt + (size_t)(sp0 + (s4 << 2)) * 15;

  float4 zn;
#define ZNC(J, Zc, Ac, Bc, Cc, Dc)                                           \
  {                                                                          \
    const float* wp = wr + (J) * 15;                                         \
    Zc = Ac * wp[iA] + Bc * wp[iB] + Cc * wp[i64] + Dc * wp[i128];           \
  }
  ZNC(0, zn.x, uA.x, uB.x, u64.x, u128.x)
  ZNC(1, zn.y, uA.y, uB.y, u64.y, u128.y)
  ZNC(2, zn.z, uA.z, uB.z, u64.z, u128.z)
  ZNC(3, zn.w, uA.w, uB.w, u64.w, u128.w)
#undef ZNC

  // ---- Reduce zn/sq over the 4 c0 classes sharing s4 (bits 4,5).
  zn = add4(zn, shx4(zn, 16));
  sq = add4(sq, shx4(sq, 16));
  zn = add4(zn, shx4(zn, 32));
  sq = add4(sq, shx4(sq, 32));

  // ---- Gate per spatial: var = sq/15; z = zn/std; gate = sigmoid(z).
  float4 g;
#define GATE(ZNc, SQc, Gc)                                                   \
  {                                                                          \
    const float inv = 1.f / sqrtf(SQc * (1.f / 15.f));                       \
    Gc = 1.f / (1.f + __expf(-(ZNc * inv)));                                 \
  }
  GATE(zn.x, sq.x, g.x)
  GATE(zn.y, sq.y, g.y)
  GATE(zn.z, sq.z, g.z)
  GATE(zn.w, sq.w, g.w)
#undef GATE

  // ---- Multiply registers by gate, store (256 B contiguous per row/instr).
  #pragma unroll
  for (int i = 0; i < 16; ++i) {
    float4 vv = v[i];
    vv.x *= g.x; vv.y *= g.y; vv.z *= g.z; vv.w *= g.w;
    *(float4*)(ob + (size_t)i * HW_) = vv;
  }
}

extern "C" void kernel_launch(void* const* d_in, const int* in_sizes, int n_in,
                              void* d_out, int out_size, void* d_ws, size_t ws_size,
                              hipStream_t stream) {
  const float* x = (const float*)d_in[0];      // [64,256,3136] fp32
  const float* w = (const float*)d_in[1];      // [3136,15] fp32
  float* out = (float*)d_out;                  // [64,256,3136] fp32
  (void)in_sizes; (void)n_in; (void)out_size; (void)d_ws; (void)ws_size;

  dim3 grid(B_ * TPI_);   // 64 * 49 = 3136 blocks
  dim3 block(256);
  ppca_fused<<<grid, block, 0, stream>>>(x, w, out);
}